// Round 2
// baseline (532.836 us; speedup 1.0000x reference)
//
#include <hip/hip_runtime.h>
#include <math.h>

// Problem constants (from reference): B=16, L=4096, H=512, D=2H=1024
#define NB 16
#define NL 4096
#define ND 1024
#define CHUNKS 64            // L split for context partials
#define ROWS_PER_CHUNK (NL / CHUNKS)   // 64

// tanh(x) = 1 - 2/(exp(2x)+1); robust at both tails (exp->0 => -1, exp->inf => 1)
__device__ __forceinline__ float fast_tanh(float x) {
    float e = __expf(2.0f * x);
    return 1.0f - 2.0f / (e + 1.0f);
}

// ---------------------------------------------------------------------------
// K1: dec_feature[b][d] = b_feat[d] + sum_k dec_hidden[b][k] * W_feat[d][k]
// one wave per (b,d); 4096 blocks x 256 thr (4 waves)
// ---------------------------------------------------------------------------
__global__ __launch_bounds__(256) void k_dec_feature(
    const float* __restrict__ dec_hidden,   // [B][D]
    const float* __restrict__ W_feat,       // [D][D]
    const float* __restrict__ b_feat,       // [D]
    float* __restrict__ dec_feature)        // [B][D]
{
    int gw   = blockIdx.x * 4 + (threadIdx.x >> 6);   // 0..16383
    int lane = threadIdx.x & 63;
    int d = gw >> 4;                                   // 0..1023
    int b = gw & 15;                                   // 0..15
    const float4* wrow = (const float4*)(W_feat + (size_t)d * ND);
    const float4* hrow = (const float4*)(dec_hidden + (size_t)b * ND);
    float acc = 0.f;
#pragma unroll
    for (int i = 0; i < 4; ++i) {
        float4 w = wrow[i * 64 + lane];
        float4 h = hrow[i * 64 + lane];
        acc += w.x * h.x + w.y * h.y + w.z * h.z + w.w * h.w;
    }
#pragma unroll
    for (int off = 32; off > 0; off >>= 1)
        acc += __shfl_down(acc, off);
    if (lane == 0)
        dec_feature[b * ND + d] = acc + b_feat[d];
}

// ---------------------------------------------------------------------------
// K2: score[b][l] = sum_d tanh(enc_feature[b][l][d] + dec_feature[b][d]
//                              + coverage[b][l]*w_cov[d]) * w_score[d]
// one wave per row; 16384 blocks x 256 thr. Streams enc_feature (256 MB).
// ---------------------------------------------------------------------------
__global__ __launch_bounds__(256) void k_score(
    const float* __restrict__ enc_feature,  // [B][L][D]
    const float* __restrict__ dec_feature,  // [B][D]
    const float* __restrict__ coverage,     // [B][L]
    const float* __restrict__ w_cov,        // [D]
    const float* __restrict__ w_score,      // [D]
    float* __restrict__ score)              // [B][L]
{
    int gw   = blockIdx.x * 4 + (threadIdx.x >> 6);   // row id 0..65535
    int lane = threadIdx.x & 63;
    int b = gw >> 12;
    const float4* erow = (const float4*)(enc_feature + (size_t)gw * ND);
    const float4* frow = (const float4*)(dec_feature + (size_t)b * ND);
    const float4* wc   = (const float4*)w_cov;
    const float4* wsc  = (const float4*)w_score;
    float cov = coverage[gw];
    float acc = 0.f;
#pragma unroll
    for (int i = 0; i < 4; ++i) {
        float4 e = erow[i * 64 + lane];
        float4 f = frow[i * 64 + lane];
        float4 c = wc [i * 64 + lane];
        float4 s = wsc[i * 64 + lane];
        acc += fast_tanh(e.x + f.x + cov * c.x) * s.x;
        acc += fast_tanh(e.y + f.y + cov * c.y) * s.y;
        acc += fast_tanh(e.z + f.z + cov * c.z) * s.z;
        acc += fast_tanh(e.w + f.w + cov * c.w) * s.w;
    }
#pragma unroll
    for (int off = 32; off > 0; off >>= 1)
        acc += __shfl_down(acc, off);
    if (lane == 0)
        score[gw] = acc;
}

// ---------------------------------------------------------------------------
// K3: per-batch masked softmax + renormalize + new_coverage.
// attn = exp(s-max)*mask / sum(exp(s-max)*mask)   (softmax Z cancels)
// one block per b; 16 blocks x 256 thr
// ---------------------------------------------------------------------------
__global__ __launch_bounds__(256) void k_softmax(
    const float* __restrict__ score,     // [B][L]
    const float* __restrict__ enc_mask,  // [B][L]
    const float* __restrict__ coverage,  // [B][L]
    float* __restrict__ attn,            // [B][L] (d_out)
    float* __restrict__ new_cov)         // [B][L] (d_out)
{
    __shared__ float s_em[NL];           // 16 KB
    __shared__ float s_red[4];
    __shared__ float s_sum[4];
    int b = blockIdx.x;
    int t = threadIdx.x;
    const float* srow = score    + (size_t)b * NL;
    const float* mrow = enc_mask + (size_t)b * NL;
    const float* crow = coverage + (size_t)b * NL;

    float m = -INFINITY;
    for (int i = t; i < NL; i += 256) m = fmaxf(m, srow[i]);
#pragma unroll
    for (int off = 32; off > 0; off >>= 1) m = fmaxf(m, __shfl_xor(m, off));
    if ((t & 63) == 0) s_red[t >> 6] = m;
    __syncthreads();
    float bm = fmaxf(fmaxf(s_red[0], s_red[1]), fmaxf(s_red[2], s_red[3]));

    float sum = 0.f;
    for (int i = t; i < NL; i += 256) {
        float em = __expf(srow[i] - bm) * mrow[i];
        s_em[i] = em;
        sum += em;
    }
#pragma unroll
    for (int off = 32; off > 0; off >>= 1) sum += __shfl_xor(sum, off);
    if ((t & 63) == 0) s_sum[t >> 6] = sum;
    __syncthreads();
    float inv = 1.0f / (s_sum[0] + s_sum[1] + s_sum[2] + s_sum[3]);

    for (int i = t; i < NL; i += 256) {
        float a = s_em[i] * inv;
        attn   [(size_t)b * NL + i] = a;
        new_cov[(size_t)b * NL + i] = a + crow[i];
    }
}

// ---------------------------------------------------------------------------
// K4: context partials: partial[b][c][d] = sum_{l in chunk c} attn[b][l]*enc_output[b][l][d]
// 1024 blocks x 256 thr; thread owns 4 consecutive d (float4). Streams enc_output (256 MB).
// ---------------------------------------------------------------------------
__global__ __launch_bounds__(256) void k_context_partial(
    const float* __restrict__ enc_output,  // [B][L][D]
    const float* __restrict__ attn,        // [B][L]
    float* __restrict__ partial)           // [B*CHUNKS][D]
{
    int bc = blockIdx.x;         // 0..1023
    int b  = bc >> 6;
    int c  = bc & 63;
    int t  = threadIdx.x;        // 0..255 -> d = 4t
    int l0 = c * ROWS_PER_CHUNK;
    const float4* base = (const float4*)(enc_output + ((size_t)(b * NL + l0)) * ND);
    const float*  arow = attn + (size_t)b * NL + l0;
    float4 acc = make_float4(0.f, 0.f, 0.f, 0.f);
#pragma unroll 4
    for (int r = 0; r < ROWS_PER_CHUNK; ++r) {
        float  a = arow[r];
        float4 e = base[(size_t)r * 256 + t];
        acc.x += a * e.x; acc.y += a * e.y; acc.z += a * e.z; acc.w += a * e.w;
    }
    ((float4*)(partial + (size_t)bc * ND))[t] = acc;
}

// ---------------------------------------------------------------------------
// K5: context[b][d] = sum_c partial[b][c][d]   (deterministic reduce)
// 64 blocks x 256 thr
// ---------------------------------------------------------------------------
__global__ __launch_bounds__(256) void k_context_reduce(
    const float* __restrict__ partial,   // [B*CHUNKS][D]
    float* __restrict__ context)         // [B][D] (d_out)
{
    int blk = blockIdx.x;                // 0..63
    int b = blk >> 2;
    int d = (blk & 3) * 256 + threadIdx.x;
    const float* p = partial + (size_t)b * CHUNKS * ND + d;
    float acc = 0.f;
#pragma unroll 8
    for (int c = 0; c < CHUNKS; ++c) acc += p[(size_t)c * ND];
    context[(size_t)b * ND + d] = acc;
}

extern "C" void kernel_launch(void* const* d_in, const int* in_sizes, int n_in,
                              void* d_out, int out_size, void* d_ws, size_t ws_size,
                              hipStream_t stream) {
    const float* dec_hidden  = (const float*)d_in[0];   // [B][D]
    const float* enc_output  = (const float*)d_in[1];   // [B][L][D]
    const float* enc_feature = (const float*)d_in[2];   // [B][L][D]
    const float* enc_mask    = (const float*)d_in[3];   // [B][L]
    // d_in[4] = sec_attn: dead code in reference, unused
    const float* coverage    = (const float*)d_in[5];   // [B][L]
    const float* W_feat      = (const float*)d_in[6];   // [D][D]
    const float* b_feat      = (const float*)d_in[7];   // [D]
    const float* w_score     = (const float*)d_in[8];   // [D]
    const float* w_cov       = (const float*)d_in[9];   // [D]

    float* out      = (float*)d_out;
    float* attn_out = out;                        // B*L
    float* ctx_out  = out + NB * NL;              // B*D
    float* cov_out  = out + NB * NL + NB * ND;    // B*L

    float* ws          = (float*)d_ws;
    float* dec_feature = ws;                      // B*D        = 16384
    float* score       = ws + NB * ND;            // B*L        = 65536
    float* partial     = ws + NB * ND + NB * NL;  // B*64*D     = 1048576
    // total ws: ~4.5 MB

    k_dec_feature<<<dim3((NB * ND) / 4), dim3(256), 0, stream>>>(
        dec_hidden, W_feat, b_feat, dec_feature);

    k_score<<<dim3((NB * NL) / 4), dim3(256), 0, stream>>>(
        enc_feature, dec_feature, coverage, w_cov, w_score, score);

    k_softmax<<<dim3(NB), dim3(256), 0, stream>>>(
        score, enc_mask, coverage, attn_out, cov_out);

    k_context_partial<<<dim3(NB * CHUNKS), dim3(256), 0, stream>>>(
        enc_output, attn_out, partial);

    k_context_reduce<<<dim3((NB * ND) / 256), dim3(256), 0, stream>>>(
        partial, ctx_out);
}

// Round 5
// 513.498 us; speedup vs baseline: 1.0377x; 1.0377x over previous
//
#include <hip/hip_runtime.h>
#include <math.h>

// Problem constants (from reference): B=16, L=4096, H=512, D=2H=1024
#define NB 16
#define NL 4096
#define ND 1024
#define CHUNKS 64                      // L split for context partials
#define ROWS_PER_CHUNK (NL / CHUNKS)   // 64

// tanh(x) = 1 - 2/(exp(2x)+1); robust at both tails
__device__ __forceinline__ float fast_tanh(float x) {
    float e = __expf(2.0f * x);
    return 1.0f - 2.0f / (e + 1.0f);
}

// __builtin_nontemporal_load rejects HIP_vector_type; use a clang native vector.
typedef float nativef4 __attribute__((ext_vector_type(4)));

__device__ __forceinline__ float4 nt_load4(const float4* p) {
    nativef4 v = __builtin_nontemporal_load((const nativef4*)p);
    return make_float4(v.x, v.y, v.z, v.w);
}

// ---------------------------------------------------------------------------
// K1: dec_feature[b][d] = b_feat[d] + sum_k dec_hidden[b][k] * W_feat[d][k]
// one wave per (b,d); 4096 blocks x 256 thr
// ---------------------------------------------------------------------------
__global__ __launch_bounds__(256) void k_dec_feature(
    const float* __restrict__ dec_hidden,   // [B][D]
    const float* __restrict__ W_feat,       // [D][D]
    const float* __restrict__ b_feat,       // [D]
    float* __restrict__ dec_feature)        // [B][D]
{
    int gw   = blockIdx.x * 4 + (threadIdx.x >> 6);   // 0..16383
    int lane = threadIdx.x & 63;
    int d = gw >> 4;
    int b = gw & 15;
    const float4* wrow = (const float4*)(W_feat + (size_t)d * ND);
    const float4* hrow = (const float4*)(dec_hidden + (size_t)b * ND);
    float acc = 0.f;
#pragma unroll
    for (int i = 0; i < 4; ++i) {
        float4 w = wrow[i * 64 + lane];
        float4 h = hrow[i * 64 + lane];
        acc += w.x * h.x + w.y * h.y + w.z * h.z + w.w * h.w;
    }
#pragma unroll
    for (int off = 32; off > 0; off >>= 1)
        acc += __shfl_down(acc, off);
    if (lane == 0)
        dec_feature[b * ND + d] = acc + b_feat[d];
}

// ---------------------------------------------------------------------------
// K2: score[b][l] = sum_d tanh(enc_f[b][l][d] + dec_f[b][d] + cov[b][l]*w_cov[d]) * w_score[d]
// 4 rows per wave: dec_f/w_cov/w_score fragments loaded ONCE per wave,
// reused for 4 rows. 4096 blocks x 256 thr. Streams enc_feature (256 MB).
// ---------------------------------------------------------------------------
__global__ __launch_bounds__(256) void k_score(
    const float* __restrict__ enc_feature,  // [B][L][D]
    const float* __restrict__ dec_feature,  // [B][D]
    const float* __restrict__ coverage,     // [B][L]
    const float* __restrict__ w_cov,        // [D]
    const float* __restrict__ w_score,      // [D]
    float* __restrict__ score)              // [B][L]
{
    int wid  = blockIdx.x * 4 + (threadIdx.x >> 6);   // 0..16383
    int lane = threadIdx.x & 63;
    int r0 = wid * 4;                                  // first of 4 rows (same b: 4096%4==0)
    int b  = r0 >> 12;

    const float4* frow = (const float4*)(dec_feature + (size_t)b * ND);
    const float4* wc   = (const float4*)w_cov;
    const float4* wsc  = (const float4*)w_score;
    float4 f4[4], c4[4], s4[4];
#pragma unroll
    for (int i = 0; i < 4; ++i) {
        f4[i] = frow[i * 64 + lane];
        c4[i] = wc  [i * 64 + lane];
        s4[i] = wsc [i * 64 + lane];
    }

#pragma unroll
    for (int r = 0; r < 4; ++r) {
        int row = r0 + r;
        float cov = coverage[row];
        const float4* erow = (const float4*)(enc_feature + (size_t)row * ND);
        float acc = 0.f;
#pragma unroll
        for (int i = 0; i < 4; ++i) {
            float4 e = nt_load4(&erow[i * 64 + lane]);
            acc += fast_tanh(e.x + f4[i].x + cov * c4[i].x) * s4[i].x;
            acc += fast_tanh(e.y + f4[i].y + cov * c4[i].y) * s4[i].y;
            acc += fast_tanh(e.z + f4[i].z + cov * c4[i].z) * s4[i].z;
            acc += fast_tanh(e.w + f4[i].w + cov * c4[i].w) * s4[i].w;
        }
#pragma unroll
        for (int off = 32; off > 0; off >>= 1)
            acc += __shfl_down(acc, off);
        if (lane == 0)
            score[row] = acc;
    }
}

// ---------------------------------------------------------------------------
// K3a: per-chunk softmax partials. 256 chunks of 256 elems; one wave each.
// pmax[w] = max over chunk (unmasked, matches ref stability); psum[w] = sum exp(s-pmax)*mask
// 64 blocks x 256 thr
// ---------------------------------------------------------------------------
__global__ __launch_bounds__(256) void k_stats(
    const float* __restrict__ score,     // [B][L]
    const float* __restrict__ enc_mask,  // [B][L]
    float* __restrict__ pmax,            // [256]
    float* __restrict__ psum)            // [256]
{
    int w    = blockIdx.x * 4 + (threadIdx.x >> 6);   // chunk id 0..255
    int lane = threadIdx.x & 63;
    int b = w >> 4, j = w & 15;
    const float4* s4 = (const float4*)(score    + (size_t)b * NL + j * 256);
    const float4* m4 = (const float4*)(enc_mask + (size_t)b * NL + j * 256);
    float4 s  = s4[lane];
    float4 mk = m4[lane];
    float mx = fmaxf(fmaxf(s.x, s.y), fmaxf(s.z, s.w));
#pragma unroll
    for (int off = 32; off > 0; off >>= 1)
        mx = fmaxf(mx, __shfl_xor(mx, off));
    float es = __expf(s.x - mx) * mk.x + __expf(s.y - mx) * mk.y
             + __expf(s.z - mx) * mk.z + __expf(s.w - mx) * mk.w;
#pragma unroll
    for (int off = 32; off > 0; off >>= 1)
        es += __shfl_xor(es, off);
    if (lane == 0) { pmax[w] = mx; psum[w] = es; }
}

// ---------------------------------------------------------------------------
// K3b: combine 16 partials per batch -> Mb[b], invb[b] = 1/sum.  1 block x 256 thr
// ---------------------------------------------------------------------------
__global__ __launch_bounds__(256) void k_combine(
    const float* __restrict__ pmax,
    const float* __restrict__ psum,
    float* __restrict__ Mb,              // [16]
    float* __restrict__ invb)            // [16]
{
    int t = threadIdx.x;
    int b = t >> 4, j = t & 15;
    float m = pmax[b * 16 + j];
    float s = psum[b * 16 + j];
    float M = m;
#pragma unroll
    for (int off = 8; off > 0; off >>= 1)
        M = fmaxf(M, __shfl_xor(M, off, 16));
    float sc = s * __expf(m - M);
#pragma unroll
    for (int off = 8; off > 0; off >>= 1)
        sc += __shfl_xor(sc, off, 16);
    if (j == 0) { Mb[b] = M; invb[b] = 1.0f / sc; }
}

// ---------------------------------------------------------------------------
// K4: fused attn/new_cov emission + context partials.
// Block (b,c): rows l0..l0+63. Threads 0..63 compute attn for their row,
// write attn_out/cov_out, stash in LDS; all 256 threads then accumulate
// partial[b][c][d] = sum_r attn[r] * enc_output[b][l0+r][d].
// 1024 blocks x 256 thr. Streams enc_output (256 MB).
// ---------------------------------------------------------------------------
__global__ __launch_bounds__(256) void k_context_attn(
    const float* __restrict__ enc_output,  // [B][L][D]
    const float* __restrict__ score,       // [B][L]
    const float* __restrict__ enc_mask,    // [B][L]
    const float* __restrict__ coverage,    // [B][L]
    const float* __restrict__ Mb,          // [16]
    const float* __restrict__ invb,        // [16]
    float* __restrict__ attn_out,          // [B][L] (d_out)
    float* __restrict__ cov_out,           // [B][L] (d_out)
    float* __restrict__ partial)           // [B*CHUNKS][D]
{
    __shared__ float s_a[ROWS_PER_CHUNK];
    int bc = blockIdx.x;          // 0..1023
    int b  = bc >> 6;
    int c  = bc & 63;
    int t  = threadIdx.x;
    int l0 = c * ROWS_PER_CHUNK;

    float M   = Mb[b];
    float inv = invb[b];
    if (t < ROWS_PER_CHUNK) {
        size_t l = (size_t)b * NL + l0 + t;
        float a = __expf(score[l] - M) * enc_mask[l] * inv;
        s_a[t] = a;
        attn_out[l] = a;
        cov_out [l] = a + coverage[l];
    }
    __syncthreads();

    const float4* base = (const float4*)(enc_output + ((size_t)(b * NL + l0)) * ND);
    float4 acc = make_float4(0.f, 0.f, 0.f, 0.f);
#pragma unroll 4
    for (int r = 0; r < ROWS_PER_CHUNK; ++r) {
        float  a = s_a[r];
        float4 e = nt_load4(&base[(size_t)r * 256 + t]);
        acc.x += a * e.x; acc.y += a * e.y; acc.z += a * e.z; acc.w += a * e.w;
    }
    ((float4*)(partial + (size_t)bc * ND))[t] = acc;
}

// ---------------------------------------------------------------------------
// K5: context[b][d] = sum_c partial[b][c][d]   (deterministic reduce)
// 64 blocks x 256 thr
// ---------------------------------------------------------------------------
__global__ __launch_bounds__(256) void k_context_reduce(
    const float* __restrict__ partial,   // [B*CHUNKS][D]
    float* __restrict__ context)         // [B][D] (d_out)
{
    int blk = blockIdx.x;                // 0..63
    int b = blk >> 2;
    int d = (blk & 3) * 256 + threadIdx.x;
    const float* p = partial + (size_t)b * CHUNKS * ND + d;
    float acc = 0.f;
#pragma unroll 8
    for (int c = 0; c < CHUNKS; ++c) acc += p[(size_t)c * ND];
    context[(size_t)b * ND + d] = acc;
}

extern "C" void kernel_launch(void* const* d_in, const int* in_sizes, int n_in,
                              void* d_out, int out_size, void* d_ws, size_t ws_size,
                              hipStream_t stream) {
    const float* dec_hidden  = (const float*)d_in[0];   // [B][D]
    const float* enc_output  = (const float*)d_in[1];   // [B][L][D]
    const float* enc_feature = (const float*)d_in[2];   // [B][L][D]
    const float* enc_mask    = (const float*)d_in[3];   // [B][L]
    // d_in[4] = sec_attn: dead code in reference, unused
    const float* coverage    = (const float*)d_in[5];   // [B][L]
    const float* W_feat      = (const float*)d_in[6];   // [D][D]
    const float* b_feat      = (const float*)d_in[7];   // [D]
    const float* w_score     = (const float*)d_in[8];   // [D]
    const float* w_cov       = (const float*)d_in[9];   // [D]

    float* out      = (float*)d_out;
    float* attn_out = out;                        // B*L
    float* ctx_out  = out + NB * NL;              // B*D
    float* cov_out  = out + NB * NL + NB * ND;    // B*L

    float* ws          = (float*)d_ws;
    float* dec_feature = ws;                              // 16384
    float* score       = dec_feature + NB * ND;           // 65536
    float* partial     = score + NB * NL;                 // 1048576
    float* pmax        = partial + NB * CHUNKS * ND;      // 256
    float* psum        = pmax + 256;                      // 256
    float* Mb          = psum + 256;                      // 16
    float* invb        = Mb + 16;                         // 16
    // total ws ~4.5 MB

    k_dec_feature<<<dim3((NB * ND) / 4), dim3(256), 0, stream>>>(
        dec_hidden, W_feat, b_feat, dec_feature);

    k_score<<<dim3((NB * NL) / 16), dim3(256), 0, stream>>>(
        enc_feature, dec_feature, coverage, w_cov, w_score, score);

    k_stats<<<dim3(64), dim3(256), 0, stream>>>(score, enc_mask, pmax, psum);

    k_combine<<<dim3(1), dim3(256), 0, stream>>>(pmax, psum, Mb, invb);

    k_context_attn<<<dim3(NB * CHUNKS), dim3(256), 0, stream>>>(
        enc_output, score, enc_mask, coverage, Mb, invb,
        attn_out, cov_out, partial);

    k_context_reduce<<<dim3((NB * ND) / 256), dim3(256), 0, stream>>>(
        partial, ctx_out);
}